// Round 14
// baseline (350.775 us; speedup 1.0000x reference)
//
#include <hip/hip_runtime.h>
#include <math.h>

#define NN 4096
#define SS 2048
#define DD 128
#define NADJ 2
#define MAXNNZ 64
#define HB 2048   // half-block width (cols per conv block)

typedef short v8s __attribute__((ext_vector_type(8)));
typedef float v4f __attribute__((ext_vector_type(4)));

__device__ __forceinline__ float softplusf(float x) {
    if (x > 20.f) return x;
    if (x < -20.f) return expf(x);
    return log1pf(expf(x));
}

__device__ __forceinline__ ushort f2bf(float f) {
    unsigned int u = __float_as_uint(f);
    unsigned int r = (u + 0x7fff + ((u >> 16) & 1)) >> 16;  // RNE
    return (ushort)r;
}
__device__ __forceinline__ float bf2f(ushort h) {
    return __uint_as_float(((unsigned int)h) << 16);
}
__device__ __forceinline__ float blo(unsigned int u) { return __uint_as_float(u << 16); }
__device__ __forceinline__ float bhi(unsigned int u) { return __uint_as_float(u & 0xffff0000u); }

// ---------------- params + zero sums ----------------
__global__ void params_kernel(const float* rls, const float* rvw, const float* rsw,
                              const float* rsb, const float* rsa, const float* rta,
                              float* params, double* sums) {
    if (threadIdx.x == 0) {
        float ls = softplusf(rls[0]);
        float vw = softplusf(rvw[0]);
        float sw = softplusf(rsw[0]);
        float sb = softplusf(rsb[0]);
        float a0 = softplusf(rsa[0]) * softplusf(rta[0]);
        float a1 = softplusf(rsa[1]) * softplusf(rta[1]);
        float vw2 = vw * vw, sw2 = sw * sw, sb2 = sb * sb;
        params[0] = 1.f / ls;
        params[1] = vw2 * sb2 * (a0 + a1);  // c_add
        params[2] = vw2 * sw2 * a0;         // w0
        params[3] = vw2 * sw2 * a1;         // w1
        sums[0] = 0.0; sums[1] = 0.0; sums[2] = 0.0;
    }
}

// ---------------- xb = bf16(feat/ls), xn = ||xb_row||^2 ----------------
__global__ void xb_kernel(const float* feat, const float* params, ushort* xb, float* xn) {
    int r = blockIdx.x;
    int l = threadIdx.x;  // 64 lanes
    float inv_ls = params[0];
    ushort h0 = f2bf(feat[r * DD + l] * inv_ls);
    ushort h1 = f2bf(feat[r * DD + 64 + l] * inv_ls);
    xb[r * DD + l] = h0;
    xb[r * DD + 64 + l] = h1;
    float v0 = bf2f(h0), v1 = bf2f(h1);
    float s = v0 * v0 + v1 * v1;
    for (int off = 32; off; off >>= 1) s += __shfl_xor(s, off);
    if (l == 0) xn[r] = s;
}

// ---------------- C0 = bf16(exp(-0.5 * sqdist)) via bf16 MFMA ----------------
__global__ __launch_bounds__(256) void c0_mfma_kernel(const ushort* xb, const float* xn,
                                                      ushort* C0b) {
    __shared__ float xr[128], xc[128];
    int t = threadIdx.x;
    int r0 = blockIdx.y * 128, c0 = blockIdx.x * 128;
    if (t < 128) xr[t] = xn[r0 + t];
    else xc[t - 128] = xn[c0 + (t - 128)];
    __syncthreads();

    int w = t >> 6, l = t & 63;
    int wr = w >> 1, wc = w & 1;
    int lr = l & 15;
    int lk = (l >> 4) * 8;
    const ushort* pa = xb + (size_t)(r0 + wr * 64 + lr) * DD + lk;
    const ushort* pb = xb + (size_t)(c0 + wc * 64 + lr) * DD + lk;

    v4f acc[4][4] = {};
    for (int ks = 0; ks < 4; ks++) {
        v8s a[4], b[4];
        for (int m = 0; m < 4; m++) a[m] = *(const v8s*)(pa + (size_t)m * 16 * DD + ks * 32);
        for (int n = 0; n < 4; n++) b[n] = *(const v8s*)(pb + (size_t)n * 16 * DD + ks * 32);
        for (int m = 0; m < 4; m++)
            for (int n = 0; n < 4; n++)
                acc[m][n] = __builtin_amdgcn_mfma_f32_16x16x32_bf16(a[m], b[n], acc[m][n], 0, 0, 0);
    }

    int rbase = wr * 64;
    int cbase = wc * 64;
    for (int m = 0; m < 4; m++) {
        for (int n = 0; n < 4; n++) {
            int ocol = cbase + n * 16 + lr;
            float xnc = xc[ocol];
            for (int j = 0; j < 4; j++) {
                int orow = rbase + m * 16 + (l >> 4) * 4 + j;
                float sq = xr[orow] + xnc - 2.f * acc[m][n][j];
                sq = fmaxf(sq, 0.f);
                C0b[(size_t)(r0 + orow) * NN + c0 + ocol] = f2bf(expf(-0.5f * sq));
            }
        }
    }
}

// ---------------- CSR extraction (block-masked), deterministic ----------------
__global__ void extract_kernel(const float* adj, int* nnzc, int* colsa) {
    __shared__ int sc[MAXNNZ];
    int b = blockIdx.x;        // a*NN + r
    int i = b >> 12;
    int r = b & (NN - 1);
    int lane = threadIdx.x;    // 64
    int base = (r < SS) ? 0 : SS;
    const float* arow = adj + ((size_t)i * NN + r) * NN + base;
    int cnt = 0;
    for (int it = 0; it < SS / 64; ++it) {
        int c = it * 64 + lane;
        float v = arow[c];
        unsigned long long m = __ballot(v != 0.f);
        if (v != 0.f) {
            int pos = cnt + __popcll(m & ((1ull << lane) - 1ull));
            if (pos < MAXNNZ) sc[pos] = c;  // relative col
        }
        cnt += __popcll(m);
    }
    if (cnt > MAXNNZ) cnt = MAXNNZ;
    __syncthreads();
    if (lane < cnt) colsa[(size_t)b * MAXNNZ + lane] = base + sc[lane];
    if (lane == 0) nnzc[b] = cnt;
}

// ---------------- merge both adjacencies into one byte-offset list per col ----------------
__global__ void merge_kernel(const int* nnzc, const int* colsa, ushort* moff, ushort* colinfo) {
    int c = blockIdx.x * 256 + threadIdx.x;
    if (c >= NN) return;
    int base = (c < SS) ? 0 : SS;
    int n0 = nnzc[c], n1 = nnzc[NN + c];
    int c0 = n0 < 8 ? n0 : 8;
    int c1 = n1 < 8 ? n1 : 8;
    ushort e[16];
    #pragma unroll
    for (int i = 0; i < 16; i++) e[i] = 8192;
    for (int i = 0; i < c0; i++)
        e[i] = (ushort)((colsa[(size_t)c * MAXNNZ + i] - base) * 4);
    for (int i = 0; i < c1; i++)
        e[c0 + i] = (ushort)((2056 + colsa[(size_t)(NN + c) * MAXNNZ + i] - base) * 4);
    uint4* mo = (uint4*)(moff + (size_t)c * 16);
    mo[0] = *(uint4*)&e[0];
    mo[1] = *(uint4*)&e[8];
    colinfo[c] = (ushort)((n0 > 8 || n1 > 8) ? 1 : 0);
}

// ---------------- colcnt_a[j] = #{r : j in nbr_a(r)} ----------------
__global__ void colcnt_kernel(const int* nnzc, const int* colsa, int* colcnt) {
    int b = blockIdx.x * 256 + threadIdx.x;  // a*NN + r
    if (b >= 2 * NN) return;
    int cnt = nnzc[b];
    const int* crow = colsa + (size_t)b * MAXNNZ;
    int abase = (b >> 12) << 12;  // a*NN
    for (int k = 0; k < cnt; k++) atomicAdd(&colcnt[abase + crow[k]], 1);
}

// ---------------- diag of layer-1 K -> svec (double gather on bf16 C0) ----------------
__global__ void diag1_kernel(const ushort* C0b, const int* nnzc, const int* colsa,
                             const float* params, float* svec) {
    int t = threadIdx.x;
    int r = blockIdx.x * 4 + (t >> 6);
    int lane = t & 63;
    float c_add = params[1], w0 = params[2], w1 = params[3];
    float s = 0.f;
    for (int a = 0; a < 2; a++) {
        int b = a * NN + r;
        int cnt = nnzc[b];
        const int* crow = colsa + (size_t)b * MAXNNZ;
        int myk = crow[(lane < cnt) ? lane : 0];
        float wa = a ? w1 : w0;
        float acc = 0.f;
        for (int j = 0; j < cnt; j++) {
            int row = crow[j];
            if (lane < cnt) acc += bf2f(C0b[(size_t)row * NN + myk]);
        }
        s += wa * acc;
    }
    for (int off = 32; off; off >>= 1) s += __shfl_xor(s, off);
    if (lane == 0) {
        float d = c_add + s;
        svec[r] = sqrtf(fmaxf(d, 0.f)) + 1e-5f;
    }
}

// ---------------- weighted K1 reduction -> block sums of K2 ----------------
// block-sum(K2)[R,C] = S^2*c_add + sum_{j,k} [w0 cc0(j)cc0(k) + w1 cc1(j)cc1(k)] K1[j,k]
__global__ __launch_bounds__(256) void msum_kernel(const ushort* __restrict__ Kb,
                                                   const int* __restrict__ colcnt,
                                                   const float* __restrict__ params,
                                                   double* sums) {
    __shared__ double rlo[256], rhi[256];
    int j = blockIdx.x;
    int t = threadIdx.x;
    float w0 = params[2], w1 = params[3];
    float wj0 = w0 * (float)colcnt[j];
    float wj1 = w1 * (float)colcnt[NN + j];
    const ushort* row = Kb + (size_t)j * NN + t * 16;
    const int* cc0 = colcnt + t * 16;
    const int* cc1 = colcnt + NN + t * 16;
    float s = 0.f;
    #pragma unroll
    for (int e = 0; e < 16; e++) {
        float kv = bf2f(row[e]);
        s += kv * (wj0 * (float)cc0[e] + wj1 * (float)cc1[e]);
    }
    bool lo = (t < 128);  // k < 2048
    rlo[t] = lo ? (double)s : 0.0;
    rhi[t] = lo ? 0.0 : (double)s;
    __syncthreads();
    for (int off = 128; off; off >>= 1) {
        if (t < off) { rlo[t] += rlo[t + off]; rhi[t] += rhi[t + off]; }
        __syncthreads();
    }
    if (t == 0) {
        if (j < SS) {
            atomicAdd(&sums[0], rlo[0]);   // ss
            atomicAdd(&sums[1], rhi[0]);   // st
        } else {
            atomicAdd(&sums[2], rhi[0]);   // tt
        }
    }
}

__global__ void means_kernel(const float* params, const double* sums, float* meansbuf) {
    if (threadIdx.x == 0) {
        const double inv = 1.0 / (2048.0 * 2048.0);
        double c_add = (double)params[1];
        meansbuf[0] = (float)(c_add + sums[0] * inv);
        meansbuf[1] = (float)(c_add + sums[1] * inv);
        meansbuf[2] = (float)(c_add + sums[2] * inv);
    }
}

// ---------------- fused conv, UPPER TRIANGLE only, G=2 row pairing ----------------
// Block (zone, by) handles rows {r0, r0+1}:
//   zone 0: r0=2by (<S), h=0, cols c_rel >= 2by   (ss upper)
//   zone 1: r0=2by (<S), h=1, full span           (st)
//   zone 2: r0=S+2by,    h=1, cols c_rel >= 2by   (tt upper)
// rs[g] = [w0*rowsum0 | 0x8 | w1*rowsum1 | 0x8] per row g. moff offsets shared by rows.
// MODE 0: relu_cov -> bf16.  MODE 1: (c_add+acc)*mean -> fp32 (pre-scaled, no sums).
template <int MODE>
__global__ __launch_bounds__(256, 4) void conv_kernel(const ushort* __restrict__ Kb,
                                                      const int* __restrict__ nnzc,
                                                      const int* __restrict__ colsa,
                                                      const uint4* __restrict__ moffq,
                                                      const ushort* __restrict__ colinfo,
                                                      const float* __restrict__ params,
                                                      const float* __restrict__ svec,
                                                      const float* __restrict__ meansbuf,
                                                      void* __restrict__ Kout_) {
    __shared__ float rs[2][4112];
    int zone = blockIdx.x;
    int by = blockIdx.y;
    int r0 = (zone == 2) ? SS + 2 * by : 2 * by;
    int h = (zone >= 1) ? 1 : 0;
    int cstart = (zone == 1) ? 0 : 2 * by;
    int cbase = h * HB;
    int t = threadIdx.x;
    float c_add = params[1], w0 = params[2], w1 = params[3];

    // ---- rowsum for both rows (R13's 16-deep preload, sequential per row) ----
    for (int g = 0; g < 2; g++) {
        int r = r0 + g;
        int cnt0 = nnzc[r], cnt1 = nnzc[NN + r];
        const int* crow0 = colsa + (size_t)r * MAXNNZ;
        const int* crow1 = colsa + (size_t)(NN + r) * MAXNNZ;
        int4 ia0 = *(const int4*)crow0;
        int4 ib0 = *(const int4*)(crow0 + 4);
        int4 ia1 = *(const int4*)crow1;
        int4 ib1 = *(const int4*)(crow1 + 4);
        int id0[8] = {ia0.x, ia0.y, ia0.z, ia0.w, ib0.x, ib0.y, ib0.z, ib0.w};
        int id1[8] = {ia1.x, ia1.y, ia1.z, ia1.w, ib1.x, ib1.y, ib1.z, ib1.w};

        uint4 v0[8], v1[8];
        #pragma unroll
        for (int j = 0; j < 8; j++) {
            int row0 = (j < cnt0) ? id0[j] : 0;   // literal 0: always-valid row
            int row1 = (j < cnt1) ? id1[j] : 0;
            v0[j] = *(const uint4*)(Kb + (size_t)row0 * NN + cbase + t * 8);
            v1[j] = *(const uint4*)(Kb + (size_t)row1 * NN + cbase + t * 8);
        }

        float acc0[8], acc1[8];
        #pragma unroll
        for (int e = 0; e < 8; e++) { acc0[e] = 0.f; acc1[e] = 0.f; }
        #pragma unroll
        for (int j = 0; j < 8; j++) {
            if (j < cnt0) {
                uint4 v = v0[j];
                acc0[0] += blo(v.x); acc0[1] += bhi(v.x);
                acc0[2] += blo(v.y); acc0[3] += bhi(v.y);
                acc0[4] += blo(v.z); acc0[5] += bhi(v.z);
                acc0[6] += blo(v.w); acc0[7] += bhi(v.w);
            }
            if (j < cnt1) {
                uint4 v = v1[j];
                acc1[0] += blo(v.x); acc1[1] += bhi(v.x);
                acc1[2] += blo(v.y); acc1[3] += bhi(v.y);
                acc1[4] += blo(v.z); acc1[5] += bhi(v.z);
                acc1[6] += blo(v.w); acc1[7] += bhi(v.w);
            }
        }
        for (int j = 8; j < cnt0; j++) {  // rare tail
            uint4 v = *(const uint4*)(Kb + (size_t)crow0[j] * NN + cbase + t * 8);
            acc0[0] += blo(v.x); acc0[1] += bhi(v.x);
            acc0[2] += blo(v.y); acc0[3] += bhi(v.y);
            acc0[4] += blo(v.z); acc0[5] += bhi(v.z);
            acc0[6] += blo(v.w); acc0[7] += bhi(v.w);
        }
        for (int j = 8; j < cnt1; j++) {
            uint4 v = *(const uint4*)(Kb + (size_t)crow1[j] * NN + cbase + t * 8);
            acc1[0] += blo(v.x); acc1[1] += bhi(v.x);
            acc1[2] += blo(v.y); acc1[3] += bhi(v.y);
            acc1[4] += blo(v.z); acc1[5] += bhi(v.z);
            acc1[6] += blo(v.w); acc1[7] += bhi(v.w);
        }
        *(float4*)&rs[g][8 * t]            = {acc0[0]*w0, acc0[1]*w0, acc0[2]*w0, acc0[3]*w0};
        *(float4*)&rs[g][8 * t + 4]        = {acc0[4]*w0, acc0[5]*w0, acc0[6]*w0, acc0[7]*w0};
        *(float4*)&rs[g][2056 + 8 * t]     = {acc1[0]*w1, acc1[1]*w1, acc1[2]*w1, acc1[3]*w1};
        *(float4*)&rs[g][2056 + 8 * t + 4] = {acc1[4]*w1, acc1[5]*w1, acc1[6]*w1, acc1[7]*w1};
        if (t < 8) { rs[g][2048 + t] = 0.f; rs[g][4104 + t] = 0.f; }
    }
    __syncthreads();

    // ---- gather: 4-col macro-batches; offsets shared by the 2 rows (8 chains) ----
    float sr0 = 0.f, sr1 = 0.f, m = 0.f;
    if (MODE == 0) { sr0 = svec[r0]; sr1 = svec[r0 + 1]; }
    else m = meansbuf[zone];
    ushort* out_b = (ushort*)Kout_;
    float* out_f = (float*)Kout_;
    const char* rsbA = (const char*)&rs[0][0];
    const char* rsbB = (const char*)&rs[1][0];
    int n_u = (HB - cstart + 255) >> 8;  // uniform slot count (1..8)

    #pragma unroll
    for (int mb = 0; mb < 2; mb++) {
        if (mb * 4 >= n_u) break;  // uniform
        int cols[4];
        uint4 mo[4][2];
        ushort ci[4];
        #pragma unroll
        for (int q = 0; q < 4; q++) {
            int u = mb * 4 + q;
            int c_rel = cstart + t + 256 * u;
            bool act = (u < n_u) && (c_rel < HB);
            int col = cbase + (act ? c_rel : 0);
            const uint4* mop = moffq + (size_t)col * 2;
            mo[q][0] = mop[0];
            mo[q][1] = mop[1];
            ci[q] = colinfo[col];
            cols[q] = act ? col : -1;
        }
        float acA[4], acB[4];
        #pragma unroll
        for (int q = 0; q < 4; q++) {
            uint4 m0 = mo[q][0], m1 = mo[q][1];
            uint o0 = m0.x & 0xffffu, o1 = m0.x >> 16;
            uint o2 = m0.y & 0xffffu, o3 = m0.y >> 16;
            uint o4 = m0.z & 0xffffu, o5 = m0.z >> 16;
            uint o6 = m0.w & 0xffffu, o7 = m0.w >> 16;
            uint o8 = m1.x & 0xffffu, o9 = m1.x >> 16;
            uint oA = m1.y & 0xffffu, oB = m1.y >> 16;
            uint oC = m1.z & 0xffffu, oD = m1.z >> 16;
            uint oE = m1.w & 0xffffu, oF = m1.w >> 16;
            float a0 = *(const float*)(rsbA + o0) + *(const float*)(rsbA + o1);
            float b0 = *(const float*)(rsbB + o0) + *(const float*)(rsbB + o1);
            float a1 = *(const float*)(rsbA + o2) + *(const float*)(rsbA + o3);
            float b1 = *(const float*)(rsbB + o2) + *(const float*)(rsbB + o3);
            float a2 = *(const float*)(rsbA + o4) + *(const float*)(rsbA + o5);
            float b2 = *(const float*)(rsbB + o4) + *(const float*)(rsbB + o5);
            float a3 = *(const float*)(rsbA + o6) + *(const float*)(rsbA + o7);
            float b3 = *(const float*)(rsbB + o6) + *(const float*)(rsbB + o7);
            float a4 = *(const float*)(rsbA + o8) + *(const float*)(rsbA + o9);
            float b4 = *(const float*)(rsbB + o8) + *(const float*)(rsbB + o9);
            float a5 = *(const float*)(rsbA + oA) + *(const float*)(rsbA + oB);
            float b5 = *(const float*)(rsbB + oA) + *(const float*)(rsbB + oB);
            float a6 = *(const float*)(rsbA + oC) + *(const float*)(rsbA + oD);
            float b6 = *(const float*)(rsbB + oC) + *(const float*)(rsbB + oD);
            float a7 = *(const float*)(rsbA + oE) + *(const float*)(rsbA + oF);
            float b7 = *(const float*)(rsbB + oE) + *(const float*)(rsbB + oF);
            acA[q] = ((a0 + a1) + (a2 + a3)) + ((a4 + a5) + (a6 + a7));
            acB[q] = ((b0 + b1) + (b2 + b3)) + ((b4 + b5) + (b6 + b7));
        }
        #pragma unroll
        for (int q = 0; q < 4; q++) {
            int col = cols[q];
            if (col < 0) continue;
            float accA = acA[q], accB = acB[q];
            if (ci[q] & 1) {  // rare overflow (>8 nnz in either adjacency)
                for (int a = 0; a < 2; a++) {
                    int b = a * NN + col;
                    int cnt = nnzc[b];
                    if (cnt > 8) {
                        const int* cp = colsa + (size_t)b * MAXNNZ;
                        for (int k = 8; k < cnt; k++) {
                            int idx = (cp[k] & (HB - 1)) + (a ? 2056 : 0);
                            accA += rs[0][idx];
                            accB += rs[1][idx];
                        }
                    }
                }
            }
            float kvA = c_add + accA;
            float kvB = c_add + accB;
            if (MODE == 0) {
                const float PIF = 3.14159265358979323846f;
                const float INV2PI = 0.15915494309189535f;
                float sc = svec[col];
                float pA = sr0 * sc, pB = sr1 * sc;
                float cA = fminf(fmaxf(kvA / pA, -1.f + 1e-6f), 1.f - 1e-6f);
                float cB = fminf(fmaxf(kvB / pB, -1.f + 1e-6f), 1.f - 1e-6f);
                float thA = acosf(cA), thB = acosf(cB);
                float stA = sqrtf(fmaxf(1.f - cA * cA, 0.f));
                float stB = sqrtf(fmaxf(1.f - cB * cB, 0.f));
                out_b[(size_t)r0 * NN + col] = f2bf(INV2PI * (stA + (PIF - thA) * cA) * pA);
                out_b[(size_t)(r0 + 1) * NN + col] = f2bf(INV2PI * (stB + (PIF - thB) * cB) * pB);
            } else {
                out_f[(size_t)r0 * NN + col] = kvA * m;
                out_f[(size_t)(r0 + 1) * NN + col] = kvB * m;
            }
        }
    }
}

// ---------------- mirror bf16 upper -> lower (tiled LDS transpose) ----------------
__global__ __launch_bounds__(256) void mirror_kernel(ushort* Kb) {
    int bi = blockIdx.x;
    int bj = blockIdx.y;
    if (bj < bi) return;
    __shared__ ushort lds[64][66];
    int R0 = bi * 64, C0 = bj * 64;
    int t = threadIdx.x;
    #pragma unroll
    for (int k = 0; k < 16; k++) {
        int lin = k * 256 + t;
        int row = lin >> 6, col = lin & 63;
        lds[row][col] = Kb[(size_t)(R0 + row) * NN + C0 + col];
    }
    __syncthreads();
    if (bj > bi) {
        #pragma unroll
        for (int k = 0; k < 16; k++) {
            int lin = k * 256 + t;
            int row = lin >> 6, col = lin & 63;
            Kb[(size_t)(C0 + row) * NN + R0 + col] = lds[col][row];
        }
    } else {
        #pragma unroll
        for (int k = 0; k < 16; k++) {
            int lin = k * 256 + t;
            int row = lin >> 6, col = lin & 63;
            if (row > col) Kb[(size_t)(R0 + row) * NN + R0 + col] = lds[col][row];
        }
    }
}

// ---------------- mirror fp32 upper -> lower (transpose fill only; upper is final) ----------------
__global__ __launch_bounds__(256) void mirror_f32_kernel(float* out) {
    int bi = blockIdx.x;
    int bj = blockIdx.y;
    if (bj < bi) return;
    __shared__ float lds[64][65];
    int R0 = bi * 64, C0 = bj * 64;
    int t = threadIdx.x;
    #pragma unroll
    for (int k = 0; k < 16; k++) {
        int lin = k * 256 + t;
        int row = lin >> 6, col = lin & 63;
        lds[row][col] = out[(size_t)(R0 + row) * NN + C0 + col];
    }
    __syncthreads();
    if (bj > bi) {
        #pragma unroll
        for (int k = 0; k < 16; k++) {
            int lin = k * 256 + t;
            int row = lin >> 6, col = lin & 63;
            out[(size_t)(C0 + row) * NN + R0 + col] = lds[col][row];
        }
    } else {
        #pragma unroll
        for (int k = 0; k < 16; k++) {
            int lin = k * 256 + t;
            int row = lin >> 6, col = lin & 63;
            if (row > col) out[(size_t)(R0 + row) * NN + R0 + col] = lds[col][row];
        }
    }
}

extern "C" void kernel_launch(void* const* d_in, const int* in_sizes, int n_in,
                              void* d_out, int out_size, void* d_ws, size_t ws_size,
                              hipStream_t stream) {
    const float* feat = (const float*)d_in[0];
    const float* adj  = (const float*)d_in[1];
    const float* rls  = (const float*)d_in[2];
    const float* rvw  = (const float*)d_in[3];
    const float* rsw  = (const float*)d_in[4];
    const float* rsb  = (const float*)d_in[5];
    const float* rsa  = (const float*)d_in[6];
    const float* rta  = (const float*)d_in[7];
    float* out = (float*)d_out;

    const size_t PNN = (size_t)NN * NN;
    char* p = (char*)d_ws;
    auto alloc = [&](size_t bytes) {
        char* r = p;
        p += (bytes + 255) & ~(size_t)255;
        return r;
    };
    float*  params   = (float*)alloc(64);
    double* sums     = (double*)alloc(64);
    float*  meansbuf = (float*)alloc(64);
    float*  xn       = (float*)alloc((size_t)NN * 4);
    float*  svec     = (float*)alloc((size_t)NN * 4);
    int*    nnzc     = (int*)alloc((size_t)2 * NN * 4);
    int*    colsa    = (int*)alloc((size_t)2 * NN * MAXNNZ * 4);
    ushort* moff     = (ushort*)alloc((size_t)NN * 16 * 2);
    ushort* colinfo  = (ushort*)alloc((size_t)NN * 2);
    int*    colcnt   = (int*)alloc((size_t)2 * NN * 4);
    ushort* xb       = (ushort*)alloc((size_t)NN * DD * 2);
    ushort* cb0      = (ushort*)alloc(PNN * 2);   // 32 MiB bf16 C0
    ushort* kb1      = (ushort*)alloc(PNN * 2);   // 32 MiB bf16 relu(K1)

    params_kernel<<<1, 64, 0, stream>>>(rls, rvw, rsw, rsb, rsa, rta, params, sums);
    hipMemsetAsync(colcnt, 0, (size_t)2 * NN * 4, stream);
    xb_kernel<<<NN, 64, 0, stream>>>(feat, params, xb, xn);
    c0_mfma_kernel<<<dim3(NN / 128, NN / 128), 256, 0, stream>>>(xb, xn, cb0);
    extract_kernel<<<NADJ * NN, 64, 0, stream>>>(adj, nnzc, colsa);
    merge_kernel<<<(NN + 255) / 256, 256, 0, stream>>>(nnzc, colsa, moff, colinfo);
    colcnt_kernel<<<(2 * NN + 255) / 256, 256, 0, stream>>>(nnzc, colsa, colcnt);

    // svec = sqrt(diag(layer1 K)) from double-gather on C0
    diag1_kernel<<<NN / 4, 256, 0, stream>>>(cb0, nnzc, colsa, params, svec);

    // layer 1 (upper, G=2): C0 (bf16) -> relu_cov(K1) (bf16), then mirror to full
    conv_kernel<0><<<dim3(3, HB / 2), 256, 0, stream>>>(cb0, nnzc, colsa, (const uint4*)moff,
                                                        colinfo, params, svec, meansbuf, kb1);
    mirror_kernel<<<dim3(64, 64), 256, 0, stream>>>(kb1);

    // block means of K2 directly from weighted K1 reduction
    msum_kernel<<<NN, 256, 0, stream>>>(kb1, colcnt, params, sums);
    means_kernel<<<1, 64, 0, stream>>>(params, sums, meansbuf);

    // layer 2 (upper, G=2): K1 (bf16) -> SCALED K2 (fp32) in d_out
    conv_kernel<1><<<dim3(3, HB / 2), 256, 0, stream>>>(kb1, nnzc, colsa, (const uint4*)moff,
                                                        colinfo, params, svec, meansbuf, out);

    // fill lower triangle (transpose only; upper already final)
    mirror_f32_kernel<<<dim3(64, 64), 256, 0, stream>>>(out);
}

// Round 15
// 279.960 us; speedup vs baseline: 1.2529x; 1.2529x over previous
//
#include <hip/hip_runtime.h>
#include <math.h>

#define NN 4096
#define SS 2048
#define DD 128
#define NADJ 2
#define MAXNNZ 64
#define HB 2048   // half-block width (cols per conv block)

typedef short v8s __attribute__((ext_vector_type(8)));
typedef float v4f __attribute__((ext_vector_type(4)));

__device__ __forceinline__ float softplusf(float x) {
    if (x > 20.f) return x;
    if (x < -20.f) return expf(x);
    return log1pf(expf(x));
}

__device__ __forceinline__ ushort f2bf(float f) {
    unsigned int u = __float_as_uint(f);
    unsigned int r = (u + 0x7fff + ((u >> 16) & 1)) >> 16;  // RNE
    return (ushort)r;
}
__device__ __forceinline__ float bf2f(ushort h) {
    return __uint_as_float(((unsigned int)h) << 16);
}
__device__ __forceinline__ float blo(unsigned int u) { return __uint_as_float(u << 16); }
__device__ __forceinline__ float bhi(unsigned int u) { return __uint_as_float(u & 0xffff0000u); }

// ---------------- params + zero sums ----------------
__global__ void params_kernel(const float* rls, const float* rvw, const float* rsw,
                              const float* rsb, const float* rsa, const float* rta,
                              float* params, double* sums) {
    if (threadIdx.x == 0) {
        float ls = softplusf(rls[0]);
        float vw = softplusf(rvw[0]);
        float sw = softplusf(rsw[0]);
        float sb = softplusf(rsb[0]);
        float a0 = softplusf(rsa[0]) * softplusf(rta[0]);
        float a1 = softplusf(rsa[1]) * softplusf(rta[1]);
        float vw2 = vw * vw, sw2 = sw * sw, sb2 = sb * sb;
        params[0] = 1.f / ls;
        params[1] = vw2 * sb2 * (a0 + a1);  // c_add
        params[2] = vw2 * sw2 * a0;         // w0
        params[3] = vw2 * sw2 * a1;         // w1
        sums[0] = 0.0; sums[1] = 0.0; sums[2] = 0.0;
    }
}

// ---------------- xb = bf16(feat/ls), xn = ||xb_row||^2 ----------------
__global__ void xb_kernel(const float* feat, const float* params, ushort* xb, float* xn) {
    int r = blockIdx.x;
    int l = threadIdx.x;  // 64 lanes
    float inv_ls = params[0];
    ushort h0 = f2bf(feat[r * DD + l] * inv_ls);
    ushort h1 = f2bf(feat[r * DD + 64 + l] * inv_ls);
    xb[r * DD + l] = h0;
    xb[r * DD + 64 + l] = h1;
    float v0 = bf2f(h0), v1 = bf2f(h1);
    float s = v0 * v0 + v1 * v1;
    for (int off = 32; off; off >>= 1) s += __shfl_xor(s, off);
    if (l == 0) xn[r] = s;
}

// ---------------- C0 = bf16(exp(-0.5 * sqdist)) via bf16 MFMA ----------------
__global__ __launch_bounds__(256) void c0_mfma_kernel(const ushort* xb, const float* xn,
                                                      ushort* C0b) {
    __shared__ float xr[128], xc[128];
    int t = threadIdx.x;
    int r0 = blockIdx.y * 128, c0 = blockIdx.x * 128;
    if (t < 128) xr[t] = xn[r0 + t];
    else xc[t - 128] = xn[c0 + (t - 128)];
    __syncthreads();

    int w = t >> 6, l = t & 63;
    int wr = w >> 1, wc = w & 1;
    int lr = l & 15;
    int lk = (l >> 4) * 8;
    const ushort* pa = xb + (size_t)(r0 + wr * 64 + lr) * DD + lk;
    const ushort* pb = xb + (size_t)(c0 + wc * 64 + lr) * DD + lk;

    v4f acc[4][4] = {};
    for (int ks = 0; ks < 4; ks++) {
        v8s a[4], b[4];
        for (int m = 0; m < 4; m++) a[m] = *(const v8s*)(pa + (size_t)m * 16 * DD + ks * 32);
        for (int n = 0; n < 4; n++) b[n] = *(const v8s*)(pb + (size_t)n * 16 * DD + ks * 32);
        for (int m = 0; m < 4; m++)
            for (int n = 0; n < 4; n++)
                acc[m][n] = __builtin_amdgcn_mfma_f32_16x16x32_bf16(a[m], b[n], acc[m][n], 0, 0, 0);
    }

    int rbase = wr * 64;
    int cbase = wc * 64;
    for (int m = 0; m < 4; m++) {
        for (int n = 0; n < 4; n++) {
            int ocol = cbase + n * 16 + lr;
            float xnc = xc[ocol];
            for (int j = 0; j < 4; j++) {
                int orow = rbase + m * 16 + (l >> 4) * 4 + j;
                float sq = xr[orow] + xnc - 2.f * acc[m][n][j];
                sq = fmaxf(sq, 0.f);
                C0b[(size_t)(r0 + orow) * NN + c0 + ocol] = f2bf(expf(-0.5f * sq));
            }
        }
    }
}

// ---------------- CSR extraction (block-masked), deterministic ----------------
__global__ void extract_kernel(const float* adj, int* nnzc, int* colsa) {
    __shared__ int sc[MAXNNZ];
    int b = blockIdx.x;        // a*NN + r
    int i = b >> 12;
    int r = b & (NN - 1);
    int lane = threadIdx.x;    // 64
    int base = (r < SS) ? 0 : SS;
    const float* arow = adj + ((size_t)i * NN + r) * NN + base;
    int cnt = 0;
    for (int it = 0; it < SS / 64; ++it) {
        int c = it * 64 + lane;
        float v = arow[c];
        unsigned long long m = __ballot(v != 0.f);
        if (v != 0.f) {
            int pos = cnt + __popcll(m & ((1ull << lane) - 1ull));
            if (pos < MAXNNZ) sc[pos] = c;  // relative col
        }
        cnt += __popcll(m);
    }
    if (cnt > MAXNNZ) cnt = MAXNNZ;
    __syncthreads();
    if (lane < cnt) colsa[(size_t)b * MAXNNZ + lane] = base + sc[lane];
    if (lane == 0) nnzc[b] = cnt;
}

// ---------------- merge both adjacencies into one byte-offset list per col ----------------
__global__ void merge_kernel(const int* nnzc, const int* colsa, ushort* moff, ushort* colinfo) {
    int c = blockIdx.x * 256 + threadIdx.x;
    if (c >= NN) return;
    int base = (c < SS) ? 0 : SS;
    int n0 = nnzc[c], n1 = nnzc[NN + c];
    int c0 = n0 < 8 ? n0 : 8;
    int c1 = n1 < 8 ? n1 : 8;
    ushort e[16];
    #pragma unroll
    for (int i = 0; i < 16; i++) e[i] = 8192;
    for (int i = 0; i < c0; i++)
        e[i] = (ushort)((colsa[(size_t)c * MAXNNZ + i] - base) * 4);
    for (int i = 0; i < c1; i++)
        e[c0 + i] = (ushort)((2056 + colsa[(size_t)(NN + c) * MAXNNZ + i] - base) * 4);
    uint4* mo = (uint4*)(moff + (size_t)c * 16);
    mo[0] = *(uint4*)&e[0];
    mo[1] = *(uint4*)&e[8];
    colinfo[c] = (ushort)((n0 > 8 || n1 > 8) ? 1 : 0);
}

// ---------------- diag of layer-1 K -> svec (double gather on bf16 C0) ----------------
__global__ void diag1_kernel(const ushort* C0b, const int* nnzc, const int* colsa,
                             const float* params, float* svec) {
    int t = threadIdx.x;
    int r = blockIdx.x * 4 + (t >> 6);
    int lane = t & 63;
    float c_add = params[1], w0 = params[2], w1 = params[3];
    float s = 0.f;
    for (int a = 0; a < 2; a++) {
        int b = a * NN + r;
        int cnt = nnzc[b];
        const int* crow = colsa + (size_t)b * MAXNNZ;
        int myk = crow[(lane < cnt) ? lane : 0];
        float wa = a ? w1 : w0;
        float acc = 0.f;
        for (int j = 0; j < cnt; j++) {
            int row = crow[j];
            if (lane < cnt) acc += bf2f(C0b[(size_t)row * NN + myk]);
        }
        s += wa * acc;
    }
    for (int off = 32; off; off >>= 1) s += __shfl_xor(s, off);
    if (lane == 0) {
        float d = c_add + s;
        svec[r] = sqrtf(fmaxf(d, 0.f)) + 1e-5f;
    }
}

// ---------------- fused conv, UPPER TRIANGLE only, G=2 row pairing ----------------
// Block (zone, by) handles rows {r0, r0+1}:
//   zone 0: r0=2by (<S), h=0, cols c_rel >= 2by   (ss upper)
//   zone 1: r0=2by (<S), h=1, full span           (st)
//   zone 2: r0=S+2by,    h=1, cols c_rel >= 2by   (tt upper)
// MODE 0: relu_cov -> bf16.  MODE 1: unscaled fp32 + block sums.
// dsum accounting (zone 0/2): rowA diag at c_rel==2by (1x), else 2x;
// rowB skips c_rel==2by (below-diag, counted by rowA's 2x at c_rel==2by+1),
// diag at c_rel==2by+1 (1x), else 2x.
template <int MODE>
__global__ __launch_bounds__(256, 4) void conv_kernel(const ushort* __restrict__ Kb,
                                                      const int* __restrict__ nnzc,
                                                      const int* __restrict__ colsa,
                                                      const uint4* __restrict__ moffq,
                                                      const ushort* __restrict__ colinfo,
                                                      const float* __restrict__ params,
                                                      const float* __restrict__ svec,
                                                      void* __restrict__ Kout_,
                                                      double* __restrict__ sums) {
    __shared__ float rs[2][4112];
    __shared__ double red[256];
    int zone = blockIdx.x;
    int by = blockIdx.y;
    int r0 = (zone == 2) ? SS + 2 * by : 2 * by;
    int h = (zone >= 1) ? 1 : 0;
    int cstart = (zone == 1) ? 0 : 2 * by;
    int cbase = h * HB;
    int t = threadIdx.x;
    float c_add = params[1], w0 = params[2], w1 = params[3];

    // ---- rowsum for both rows (16-deep preload, sequential per row) ----
    for (int g = 0; g < 2; g++) {
        int r = r0 + g;
        int cnt0 = nnzc[r], cnt1 = nnzc[NN + r];
        const int* crow0 = colsa + (size_t)r * MAXNNZ;
        const int* crow1 = colsa + (size_t)(NN + r) * MAXNNZ;
        int4 ia0 = *(const int4*)crow0;
        int4 ib0 = *(const int4*)(crow0 + 4);
        int4 ia1 = *(const int4*)crow1;
        int4 ib1 = *(const int4*)(crow1 + 4);
        int id0[8] = {ia0.x, ia0.y, ia0.z, ia0.w, ib0.x, ib0.y, ib0.z, ib0.w};
        int id1[8] = {ia1.x, ia1.y, ia1.z, ia1.w, ib1.x, ib1.y, ib1.z, ib1.w};

        uint4 v0[8], v1[8];
        #pragma unroll
        for (int j = 0; j < 8; j++) {
            int row0 = (j < cnt0) ? id0[j] : 0;   // literal 0: always-valid row
            int row1 = (j < cnt1) ? id1[j] : 0;
            v0[j] = *(const uint4*)(Kb + (size_t)row0 * NN + cbase + t * 8);
            v1[j] = *(const uint4*)(Kb + (size_t)row1 * NN + cbase + t * 8);
        }

        float acc0[8], acc1[8];
        #pragma unroll
        for (int e = 0; e < 8; e++) { acc0[e] = 0.f; acc1[e] = 0.f; }
        #pragma unroll
        for (int j = 0; j < 8; j++) {
            if (j < cnt0) {
                uint4 v = v0[j];
                acc0[0] += blo(v.x); acc0[1] += bhi(v.x);
                acc0[2] += blo(v.y); acc0[3] += bhi(v.y);
                acc0[4] += blo(v.z); acc0[5] += bhi(v.z);
                acc0[6] += blo(v.w); acc0[7] += bhi(v.w);
            }
            if (j < cnt1) {
                uint4 v = v1[j];
                acc1[0] += blo(v.x); acc1[1] += bhi(v.x);
                acc1[2] += blo(v.y); acc1[3] += bhi(v.y);
                acc1[4] += blo(v.z); acc1[5] += bhi(v.z);
                acc1[6] += blo(v.w); acc1[7] += bhi(v.w);
            }
        }
        for (int j = 8; j < cnt0; j++) {  // rare tail
            uint4 v = *(const uint4*)(Kb + (size_t)crow0[j] * NN + cbase + t * 8);
            acc0[0] += blo(v.x); acc0[1] += bhi(v.x);
            acc0[2] += blo(v.y); acc0[3] += bhi(v.y);
            acc0[4] += blo(v.z); acc0[5] += bhi(v.z);
            acc0[6] += blo(v.w); acc0[7] += bhi(v.w);
        }
        for (int j = 8; j < cnt1; j++) {
            uint4 v = *(const uint4*)(Kb + (size_t)crow1[j] * NN + cbase + t * 8);
            acc1[0] += blo(v.x); acc1[1] += bhi(v.x);
            acc1[2] += blo(v.y); acc1[3] += bhi(v.y);
            acc1[4] += blo(v.z); acc1[5] += bhi(v.z);
            acc1[6] += blo(v.w); acc1[7] += bhi(v.w);
        }
        *(float4*)&rs[g][8 * t]            = {acc0[0]*w0, acc0[1]*w0, acc0[2]*w0, acc0[3]*w0};
        *(float4*)&rs[g][8 * t + 4]        = {acc0[4]*w0, acc0[5]*w0, acc0[6]*w0, acc0[7]*w0};
        *(float4*)&rs[g][2056 + 8 * t]     = {acc1[0]*w1, acc1[1]*w1, acc1[2]*w1, acc1[3]*w1};
        *(float4*)&rs[g][2056 + 8 * t + 4] = {acc1[4]*w1, acc1[5]*w1, acc1[6]*w1, acc1[7]*w1};
        if (t < 8) { rs[g][2048 + t] = 0.f; rs[g][4104 + t] = 0.f; }
    }
    __syncthreads();

    // ---- gather: 4-col macro-batches; offsets shared by the 2 rows (8 chains) ----
    float sr0 = 0.f, sr1 = 0.f;
    if (MODE == 0) { sr0 = svec[r0]; sr1 = svec[r0 + 1]; }
    double dsum = 0.0;
    ushort* out_b = (ushort*)Kout_;
    float* out_f = (float*)Kout_;
    const char* rsbA = (const char*)&rs[0][0];
    const char* rsbB = (const char*)&rs[1][0];
    int n_u = (HB - cstart + 255) >> 8;  // uniform slot count (1..8)

    #pragma unroll
    for (int mb = 0; mb < 2; mb++) {
        if (mb * 4 >= n_u) break;  // uniform
        int cols[4];
        uint4 mo[4][2];
        ushort ci[4];
        #pragma unroll
        for (int q = 0; q < 4; q++) {
            int u = mb * 4 + q;
            int c_rel = cstart + t + 256 * u;
            bool act = (u < n_u) && (c_rel < HB);
            int col = cbase + (act ? c_rel : 0);
            const uint4* mop = moffq + (size_t)col * 2;
            mo[q][0] = mop[0];
            mo[q][1] = mop[1];
            ci[q] = colinfo[col];
            cols[q] = act ? col : -1;
        }
        float acA[4], acB[4];
        #pragma unroll
        for (int q = 0; q < 4; q++) {
            uint4 m0 = mo[q][0], m1 = mo[q][1];
            uint o0 = m0.x & 0xffffu, o1 = m0.x >> 16;
            uint o2 = m0.y & 0xffffu, o3 = m0.y >> 16;
            uint o4 = m0.z & 0xffffu, o5 = m0.z >> 16;
            uint o6 = m0.w & 0xffffu, o7 = m0.w >> 16;
            uint o8 = m1.x & 0xffffu, o9 = m1.x >> 16;
            uint oA = m1.y & 0xffffu, oB = m1.y >> 16;
            uint oC = m1.z & 0xffffu, oD = m1.z >> 16;
            uint oE = m1.w & 0xffffu, oF = m1.w >> 16;
            float a0 = *(const float*)(rsbA + o0) + *(const float*)(rsbA + o1);
            float b0 = *(const float*)(rsbB + o0) + *(const float*)(rsbB + o1);
            float a1 = *(const float*)(rsbA + o2) + *(const float*)(rsbA + o3);
            float b1 = *(const float*)(rsbB + o2) + *(const float*)(rsbB + o3);
            float a2 = *(const float*)(rsbA + o4) + *(const float*)(rsbA + o5);
            float b2 = *(const float*)(rsbB + o4) + *(const float*)(rsbB + o5);
            float a3 = *(const float*)(rsbA + o6) + *(const float*)(rsbA + o7);
            float b3 = *(const float*)(rsbB + o6) + *(const float*)(rsbB + o7);
            float a4 = *(const float*)(rsbA + o8) + *(const float*)(rsbA + o9);
            float b4 = *(const float*)(rsbB + o8) + *(const float*)(rsbB + o9);
            float a5 = *(const float*)(rsbA + oA) + *(const float*)(rsbA + oB);
            float b5 = *(const float*)(rsbB + oA) + *(const float*)(rsbB + oB);
            float a6 = *(const float*)(rsbA + oC) + *(const float*)(rsbA + oD);
            float b6 = *(const float*)(rsbB + oC) + *(const float*)(rsbB + oD);
            float a7 = *(const float*)(rsbA + oE) + *(const float*)(rsbA + oF);
            float b7 = *(const float*)(rsbB + oE) + *(const float*)(rsbB + oF);
            acA[q] = ((a0 + a1) + (a2 + a3)) + ((a4 + a5) + (a6 + a7));
            acB[q] = ((b0 + b1) + (b2 + b3)) + ((b4 + b5) + (b6 + b7));
        }
        #pragma unroll
        for (int q = 0; q < 4; q++) {
            int col = cols[q];
            if (col < 0) continue;
            float accA = acA[q], accB = acB[q];
            if (ci[q] & 1) {  // rare overflow (>8 nnz in either adjacency)
                for (int a = 0; a < 2; a++) {
                    int b = a * NN + col;
                    int cnt = nnzc[b];
                    if (cnt > 8) {
                        const int* cp = colsa + (size_t)b * MAXNNZ;
                        for (int k = 8; k < cnt; k++) {
                            int idx = (cp[k] & (HB - 1)) + (a ? 2056 : 0);
                            accA += rs[0][idx];
                            accB += rs[1][idx];
                        }
                    }
                }
            }
            float kvA = c_add + accA;
            float kvB = c_add + accB;
            if (MODE == 0) {
                const float PIF = 3.14159265358979323846f;
                const float INV2PI = 0.15915494309189535f;
                float sc = svec[col];
                float pA = sr0 * sc, pB = sr1 * sc;
                float cA = fminf(fmaxf(kvA / pA, -1.f + 1e-6f), 1.f - 1e-6f);
                float cB = fminf(fmaxf(kvB / pB, -1.f + 1e-6f), 1.f - 1e-6f);
                float thA = acosf(cA), thB = acosf(cB);
                float stA = sqrtf(fmaxf(1.f - cA * cA, 0.f));
                float stB = sqrtf(fmaxf(1.f - cB * cB, 0.f));
                out_b[(size_t)r0 * NN + col] = f2bf(INV2PI * (stA + (PIF - thA) * cA) * pA);
                out_b[(size_t)(r0 + 1) * NN + col] = f2bf(INV2PI * (stB + (PIF - thB) * cB) * pB);
            } else {
                out_f[(size_t)r0 * NN + col] = kvA;      // unscaled upper
                out_f[(size_t)(r0 + 1) * NN + col] = kvB;
                if (zone == 1) {
                    dsum += (double)kvA + (double)kvB;
                } else {
                    int c_rel = col - cbase;
                    dsum += (c_rel == 2 * by) ? (double)kvA : 2.0 * (double)kvA;
                    if (c_rel != 2 * by)
                        dsum += (c_rel == 2 * by + 1) ? (double)kvB : 2.0 * (double)kvB;
                }
            }
        }
    }

    if (MODE == 1) {
        red[t] = dsum;
        __syncthreads();
        for (int off = 128; off; off >>= 1) {
            if (t < off) red[t] += red[t + off];
            __syncthreads();
        }
        if (t == 0) atomicAdd(&sums[zone], red[0]);  // zone0->ss, zone1->st, zone2->tt
    }
}

// ---------------- mirror bf16 upper -> lower (tiled LDS transpose) ----------------
__global__ __launch_bounds__(256) void mirror_kernel(ushort* Kb) {
    int bi = blockIdx.x;
    int bj = blockIdx.y;
    if (bj < bi) return;
    __shared__ ushort lds[64][66];
    int R0 = bi * 64, C0 = bj * 64;
    int t = threadIdx.x;
    #pragma unroll
    for (int k = 0; k < 16; k++) {
        int lin = k * 256 + t;
        int row = lin >> 6, col = lin & 63;
        lds[row][col] = Kb[(size_t)(R0 + row) * NN + C0 + col];
    }
    __syncthreads();
    if (bj > bi) {
        #pragma unroll
        for (int k = 0; k < 16; k++) {
            int lin = k * 256 + t;
            int row = lin >> 6, col = lin & 63;
            Kb[(size_t)(C0 + row) * NN + R0 + col] = lds[col][row];
        }
    } else {
        #pragma unroll
        for (int k = 0; k < 16; k++) {
            int lin = k * 256 + t;
            int row = lin >> 6, col = lin & 63;
            if (row > col) Kb[(size_t)(R0 + row) * NN + R0 + col] = lds[col][row];
        }
    }
}

// ---------------- finalize: scale upper in place + write scaled transpose to lower ----------------
__global__ __launch_bounds__(256) void finalize_kernel(float* out, const double* sums) {
    int bi = blockIdx.x;
    int bj = blockIdx.y;
    if (bj < bi) return;
    __shared__ float lds[64][65];
    const double inv = 1.0 / (2048.0 * 2048.0);
    float mss = (float)(sums[0] * inv);
    float mst = (float)(sums[1] * inv);
    float mtt = (float)(sums[2] * inv);
    int R0 = bi * 64, C0 = bj * 64;
    float m = (R0 < SS) ? (C0 < SS ? mss : mst) : (C0 < SS ? mst : mtt);
    int t = threadIdx.x;
    #pragma unroll
    for (int k = 0; k < 16; k++) {
        int lin = k * 256 + t;
        int row = lin >> 6, col = lin & 63;
        lds[row][col] = out[(size_t)(R0 + row) * NN + C0 + col];
    }
    __syncthreads();
    if (bj > bi) {
        #pragma unroll
        for (int k = 0; k < 16; k++) {
            int lin = k * 256 + t;
            int row = lin >> 6, col = lin & 63;
            out[(size_t)(R0 + row) * NN + C0 + col] = m * lds[row][col];
            out[(size_t)(C0 + row) * NN + R0 + col] = m * lds[col][row];
        }
    } else {
        #pragma unroll
        for (int k = 0; k < 16; k++) {
            int lin = k * 256 + t;
            int row = lin >> 6, col = lin & 63;
            float v = (row <= col) ? lds[row][col] : lds[col][row];
            out[(size_t)(R0 + row) * NN + R0 + col] = m * v;
        }
    }
}

extern "C" void kernel_launch(void* const* d_in, const int* in_sizes, int n_in,
                              void* d_out, int out_size, void* d_ws, size_t ws_size,
                              hipStream_t stream) {
    const float* feat = (const float*)d_in[0];
    const float* adj  = (const float*)d_in[1];
    const float* rls  = (const float*)d_in[2];
    const float* rvw  = (const float*)d_in[3];
    const float* rsw  = (const float*)d_in[4];
    const float* rsb  = (const float*)d_in[5];
    const float* rsa  = (const float*)d_in[6];
    const float* rta  = (const float*)d_in[7];
    float* out = (float*)d_out;

    const size_t PNN = (size_t)NN * NN;
    char* p = (char*)d_ws;
    auto alloc = [&](size_t bytes) {
        char* r = p;
        p += (bytes + 255) & ~(size_t)255;
        return r;
    };
    float*  params   = (float*)alloc(64);
    double* sums     = (double*)alloc(64);
    float*  xn       = (float*)alloc((size_t)NN * 4);
    float*  svec     = (float*)alloc((size_t)NN * 4);
    int*    nnzc     = (int*)alloc((size_t)2 * NN * 4);
    int*    colsa    = (int*)alloc((size_t)2 * NN * MAXNNZ * 4);
    ushort* moff     = (ushort*)alloc((size_t)NN * 16 * 2);
    ushort* colinfo  = (ushort*)alloc((size_t)NN * 2);
    ushort* xb       = (ushort*)alloc((size_t)NN * DD * 2);
    ushort* cb0      = (ushort*)alloc(PNN * 2);   // 32 MiB bf16 C0
    ushort* kb1      = (ushort*)alloc(PNN * 2);   // 32 MiB bf16 relu(K1)

    params_kernel<<<1, 64, 0, stream>>>(rls, rvw, rsw, rsb, rsa, rta, params, sums);
    xb_kernel<<<NN, 64, 0, stream>>>(feat, params, xb, xn);
    c0_mfma_kernel<<<dim3(NN / 128, NN / 128), 256, 0, stream>>>(xb, xn, cb0);
    extract_kernel<<<NADJ * NN, 64, 0, stream>>>(adj, nnzc, colsa);
    merge_kernel<<<(NN + 255) / 256, 256, 0, stream>>>(nnzc, colsa, moff, colinfo);

    // svec = sqrt(diag(layer1 K)) from double-gather on C0
    diag1_kernel<<<NN / 4, 256, 0, stream>>>(cb0, nnzc, colsa, params, svec);

    // layer 1 (upper, G=2): C0 (bf16) -> relu_cov(K1) (bf16), then mirror to full
    conv_kernel<0><<<dim3(3, HB / 2), 256, 0, stream>>>(cb0, nnzc, colsa, (const uint4*)moff,
                                                        colinfo, params, svec, kb1, sums);
    mirror_kernel<<<dim3(64, 64), 256, 0, stream>>>(kb1);

    // layer 2 (upper, G=2): K1 (bf16) -> unscaled K2 (fp32) in d_out + block sums
    conv_kernel<1><<<dim3(3, HB / 2), 256, 0, stream>>>(kb1, nnzc, colsa, (const uint4*)moff,
                                                        colinfo, params, svec, out, sums);

    // scale by block means + fill lower triangle (transpose)
    finalize_kernel<<<dim3(64, 64), 256, 0, stream>>>(out, sums);
}

// Round 16
// 265.635 us; speedup vs baseline: 1.3205x; 1.0539x over previous
//
#include <hip/hip_runtime.h>
#include <math.h>

#define NN 4096
#define SS 2048
#define DD 128
#define NADJ 2
#define MAXNNZ 64
#define HB 2048   // half-block width (cols per conv block)

typedef short v8s __attribute__((ext_vector_type(8)));
typedef float v4f __attribute__((ext_vector_type(4)));

__device__ __forceinline__ float softplusf(float x) {
    if (x > 20.f) return x;
    if (x < -20.f) return expf(x);
    return log1pf(expf(x));
}

__device__ __forceinline__ ushort f2bf(float f) {
    unsigned int u = __float_as_uint(f);
    unsigned int r = (u + 0x7fff + ((u >> 16) & 1)) >> 16;  // RNE
    return (ushort)r;
}
__device__ __forceinline__ float bf2f(ushort h) {
    return __uint_as_float(((unsigned int)h) << 16);
}
__device__ __forceinline__ float blo(unsigned int u) { return __uint_as_float(u << 16); }
__device__ __forceinline__ float bhi(unsigned int u) { return __uint_as_float(u & 0xffff0000u); }

// ---------------- params + zero sums ----------------
__global__ void params_kernel(const float* rls, const float* rvw, const float* rsw,
                              const float* rsb, const float* rsa, const float* rta,
                              float* params, double* sums) {
    if (threadIdx.x == 0) {
        float ls = softplusf(rls[0]);
        float vw = softplusf(rvw[0]);
        float sw = softplusf(rsw[0]);
        float sb = softplusf(rsb[0]);
        float a0 = softplusf(rsa[0]) * softplusf(rta[0]);
        float a1 = softplusf(rsa[1]) * softplusf(rta[1]);
        float vw2 = vw * vw, sw2 = sw * sw, sb2 = sb * sb;
        params[0] = 1.f / ls;
        params[1] = vw2 * sb2 * (a0 + a1);  // c_add
        params[2] = vw2 * sw2 * a0;         // w0
        params[3] = vw2 * sw2 * a1;         // w1
        sums[0] = 0.0; sums[1] = 0.0; sums[2] = 0.0;
    }
}

// ---------------- xb = bf16(feat/ls), xn = ||xb_row||^2 ----------------
__global__ void xb_kernel(const float* feat, const float* params, ushort* xb, float* xn) {
    int r = blockIdx.x;
    int l = threadIdx.x;  // 64 lanes
    float inv_ls = params[0];
    ushort h0 = f2bf(feat[r * DD + l] * inv_ls);
    ushort h1 = f2bf(feat[r * DD + 64 + l] * inv_ls);
    xb[r * DD + l] = h0;
    xb[r * DD + 64 + l] = h1;
    float v0 = bf2f(h0), v1 = bf2f(h1);
    float s = v0 * v0 + v1 * v1;
    for (int off = 32; off; off >>= 1) s += __shfl_xor(s, off);
    if (l == 0) xn[r] = s;
}

// ---------------- C0 = bf16(exp(-0.5 * sqdist)) via bf16 MFMA ----------------
__global__ __launch_bounds__(256) void c0_mfma_kernel(const ushort* xb, const float* xn,
                                                      ushort* C0b) {
    __shared__ float xr[128], xc[128];
    int t = threadIdx.x;
    int r0 = blockIdx.y * 128, c0 = blockIdx.x * 128;
    if (t < 128) xr[t] = xn[r0 + t];
    else xc[t - 128] = xn[c0 + (t - 128)];
    __syncthreads();

    int w = t >> 6, l = t & 63;
    int wr = w >> 1, wc = w & 1;
    int lr = l & 15;
    int lk = (l >> 4) * 8;
    const ushort* pa = xb + (size_t)(r0 + wr * 64 + lr) * DD + lk;
    const ushort* pb = xb + (size_t)(c0 + wc * 64 + lr) * DD + lk;

    v4f acc[4][4] = {};
    for (int ks = 0; ks < 4; ks++) {
        v8s a[4], b[4];
        for (int m = 0; m < 4; m++) a[m] = *(const v8s*)(pa + (size_t)m * 16 * DD + ks * 32);
        for (int n = 0; n < 4; n++) b[n] = *(const v8s*)(pb + (size_t)n * 16 * DD + ks * 32);
        for (int m = 0; m < 4; m++)
            for (int n = 0; n < 4; n++)
                acc[m][n] = __builtin_amdgcn_mfma_f32_16x16x32_bf16(a[m], b[n], acc[m][n], 0, 0, 0);
    }

    int rbase = wr * 64;
    int cbase = wc * 64;
    for (int m = 0; m < 4; m++) {
        for (int n = 0; n < 4; n++) {
            int ocol = cbase + n * 16 + lr;
            float xnc = xc[ocol];
            for (int j = 0; j < 4; j++) {
                int orow = rbase + m * 16 + (l >> 4) * 4 + j;
                float sq = xr[orow] + xnc - 2.f * acc[m][n][j];
                sq = fmaxf(sq, 0.f);
                C0b[(size_t)(r0 + orow) * NN + c0 + ocol] = f2bf(expf(-0.5f * sq));
            }
        }
    }
}

// ---------------- CSR extraction (block-masked), deterministic ----------------
__global__ void extract_kernel(const float* adj, int* nnzc, int* colsa) {
    __shared__ int sc[MAXNNZ];
    int b = blockIdx.x;        // a*NN + r
    int i = b >> 12;
    int r = b & (NN - 1);
    int lane = threadIdx.x;    // 64
    int base = (r < SS) ? 0 : SS;
    const float* arow = adj + ((size_t)i * NN + r) * NN + base;
    int cnt = 0;
    for (int it = 0; it < SS / 64; ++it) {
        int c = it * 64 + lane;
        float v = arow[c];
        unsigned long long m = __ballot(v != 0.f);
        if (v != 0.f) {
            int pos = cnt + __popcll(m & ((1ull << lane) - 1ull));
            if (pos < MAXNNZ) sc[pos] = c;  // relative col
        }
        cnt += __popcll(m);
    }
    if (cnt > MAXNNZ) cnt = MAXNNZ;
    __syncthreads();
    if (lane < cnt) colsa[(size_t)b * MAXNNZ + lane] = base + sc[lane];
    if (lane == 0) nnzc[b] = cnt;
}

// ---------------- merge both adjacencies into one byte-offset list per col ----------------
__global__ void merge_kernel(const int* nnzc, const int* colsa, ushort* moff, ushort* colinfo) {
    int c = blockIdx.x * 256 + threadIdx.x;
    if (c >= NN) return;
    int base = (c < SS) ? 0 : SS;
    int n0 = nnzc[c], n1 = nnzc[NN + c];
    int c0 = n0 < 8 ? n0 : 8;
    int c1 = n1 < 8 ? n1 : 8;
    ushort e[16];
    #pragma unroll
    for (int i = 0; i < 16; i++) e[i] = 8192;
    for (int i = 0; i < c0; i++)
        e[i] = (ushort)((colsa[(size_t)c * MAXNNZ + i] - base) * 4);
    for (int i = 0; i < c1; i++)
        e[c0 + i] = (ushort)((2056 + colsa[(size_t)(NN + c) * MAXNNZ + i] - base) * 4);
    uint4* mo = (uint4*)(moff + (size_t)c * 16);
    mo[0] = *(uint4*)&e[0];
    mo[1] = *(uint4*)&e[8];
    colinfo[c] = (ushort)((n0 > 8 || n1 > 8) ? 1 : 0);
}

// ---------------- diag of layer-1 K -> svec (double gather on bf16 C0) ----------------
__global__ void diag1_kernel(const ushort* C0b, const int* nnzc, const int* colsa,
                             const float* params, float* svec) {
    int t = threadIdx.x;
    int r = blockIdx.x * 4 + (t >> 6);
    int lane = t & 63;
    float c_add = params[1], w0 = params[2], w1 = params[3];
    float s = 0.f;
    for (int a = 0; a < 2; a++) {
        int b = a * NN + r;
        int cnt = nnzc[b];
        const int* crow = colsa + (size_t)b * MAXNNZ;
        int myk = crow[(lane < cnt) ? lane : 0];
        float wa = a ? w1 : w0;
        float acc = 0.f;
        for (int j = 0; j < cnt; j++) {
            int row = crow[j];
            if (lane < cnt) acc += bf2f(C0b[(size_t)row * NN + myk]);
        }
        s += wa * acc;
    }
    for (int off = 32; off; off >>= 1) s += __shfl_xor(s, off);
    if (lane == 0) {
        float d = c_add + s;
        svec[r] = sqrtf(fmaxf(d, 0.f)) + 1e-5f;
    }
}

// ---------------- fused conv, UPPER TRIANGLE only ----------------
// launch_bounds(256,4): 128 VGPR/wave -> full rowsum preload + 4-col gather prefetch.
// SAFETY: preload clamp must be literal 0 (colsa entries beyond cnt are GARBAGE,
// including entry 0 when cnt==0 — caused R12's fault).
// zones (blockIdx.x): 0: r=by (<S), h=0, cols c_rel>=by   (ss upper)
//                     1: r=by (<S), h=1, full span        (st)
//                     2: r=S+by,    h=1, cols c_rel>=by   (tt upper)
template <int MODE>
__global__ __launch_bounds__(256, 4) void conv_kernel(const ushort* __restrict__ Kb,
                                                      const int* __restrict__ nnzc,
                                                      const int* __restrict__ colsa,
                                                      const uint4* __restrict__ moffq,
                                                      const ushort* __restrict__ colinfo,
                                                      const float* __restrict__ params,
                                                      const float* __restrict__ svec,
                                                      void* __restrict__ Kout_,
                                                      double* __restrict__ sums) {
    __shared__ float rs[4112];
    __shared__ double red[256];
    int zone = blockIdx.x;
    int by = blockIdx.y;
    int r = (zone == 2) ? SS + by : by;
    int h = (zone >= 1) ? 1 : 0;
    int cstart = (zone == 1) ? 0 : by;
    int cbase = h * HB;
    int t = threadIdx.x;
    float c_add = params[1], w0 = params[2], w1 = params[3];

    // ---- rowsum: preload ALL 16 neighbor rows into registers (max MLP) ----
    {
        int cnt0 = nnzc[r], cnt1 = nnzc[NN + r];
        const int* crow0 = colsa + (size_t)r * MAXNNZ;
        const int* crow1 = colsa + (size_t)(NN + r) * MAXNNZ;
        int4 ia0 = *(const int4*)crow0;
        int4 ib0 = *(const int4*)(crow0 + 4);
        int4 ia1 = *(const int4*)crow1;
        int4 ib1 = *(const int4*)(crow1 + 4);
        int id0[8] = {ia0.x, ia0.y, ia0.z, ia0.w, ib0.x, ib0.y, ib0.z, ib0.w};
        int id1[8] = {ia1.x, ia1.y, ia1.z, ia1.w, ib1.x, ib1.y, ib1.z, ib1.w};

        uint4 v0[8], v1[8];
        #pragma unroll
        for (int j = 0; j < 8; j++) {
            int row0 = (j < cnt0) ? id0[j] : 0;   // literal 0: always-valid row
            int row1 = (j < cnt1) ? id1[j] : 0;
            v0[j] = *(const uint4*)(Kb + (size_t)row0 * NN + cbase + t * 8);
            v1[j] = *(const uint4*)(Kb + (size_t)row1 * NN + cbase + t * 8);
        }

        float acc0[8], acc1[8];
        #pragma unroll
        for (int e = 0; e < 8; e++) { acc0[e] = 0.f; acc1[e] = 0.f; }
        #pragma unroll
        for (int j = 0; j < 8; j++) {
            if (j < cnt0) {
                uint4 v = v0[j];
                acc0[0] += blo(v.x); acc0[1] += bhi(v.x);
                acc0[2] += blo(v.y); acc0[3] += bhi(v.y);
                acc0[4] += blo(v.z); acc0[5] += bhi(v.z);
                acc0[6] += blo(v.w); acc0[7] += bhi(v.w);
            }
            if (j < cnt1) {
                uint4 v = v1[j];
                acc1[0] += blo(v.x); acc1[1] += bhi(v.x);
                acc1[2] += blo(v.y); acc1[3] += bhi(v.y);
                acc1[4] += blo(v.z); acc1[5] += bhi(v.z);
                acc1[6] += blo(v.w); acc1[7] += bhi(v.w);
            }
        }
        for (int j = 8; j < cnt0; j++) {  // rare tail
            uint4 v = *(const uint4*)(Kb + (size_t)crow0[j] * NN + cbase + t * 8);
            acc0[0] += blo(v.x); acc0[1] += bhi(v.x);
            acc0[2] += blo(v.y); acc0[3] += bhi(v.y);
            acc0[4] += blo(v.z); acc0[5] += bhi(v.z);
            acc0[6] += blo(v.w); acc0[7] += bhi(v.w);
        }
        for (int j = 8; j < cnt1; j++) {
            uint4 v = *(const uint4*)(Kb + (size_t)crow1[j] * NN + cbase + t * 8);
            acc1[0] += blo(v.x); acc1[1] += bhi(v.x);
            acc1[2] += blo(v.y); acc1[3] += bhi(v.y);
            acc1[4] += blo(v.z); acc1[5] += bhi(v.z);
            acc1[6] += blo(v.w); acc1[7] += bhi(v.w);
        }
        *(float4*)&rs[8 * t]            = {acc0[0]*w0, acc0[1]*w0, acc0[2]*w0, acc0[3]*w0};
        *(float4*)&rs[8 * t + 4]        = {acc0[4]*w0, acc0[5]*w0, acc0[6]*w0, acc0[7]*w0};
        *(float4*)&rs[2056 + 8 * t]     = {acc1[0]*w1, acc1[1]*w1, acc1[2]*w1, acc1[3]*w1};
        *(float4*)&rs[2056 + 8 * t + 4] = {acc1[4]*w1, acc1[5]*w1, acc1[6]*w1, acc1[7]*w1};
        if (t < 8) { rs[2048 + t] = 0.f; rs[4104 + t] = 0.f; }
    }
    __syncthreads();

    // ---- gather: macro-batches of 4 cols; prefetch offsets, then pure-LDS chains ----
    float sr = (MODE == 0) ? svec[r] : 0.f;
    double dsum = 0.0;
    ushort* out_b = (ushort*)Kout_;
    float* out_f = (float*)Kout_;
    const char* rsb = (const char*)rs;
    int n_u = (HB - cstart + 255) >> 8;  // uniform slot count (1..8)

    #pragma unroll
    for (int mb = 0; mb < 2; mb++) {
        if (mb * 4 >= n_u) break;  // uniform branch
        int cols[4];
        uint4 mo[4][2];
        ushort ci[4];
        #pragma unroll
        for (int q = 0; q < 4; q++) {
            int u = mb * 4 + q;
            int c_rel = cstart + t + 256 * u;
            bool act = (u < n_u) && (c_rel < HB);
            int col = cbase + (act ? c_rel : 0);
            const uint4* mop = moffq + (size_t)col * 2;
            mo[q][0] = mop[0];
            mo[q][1] = mop[1];
            ci[q] = colinfo[col];
            cols[q] = act ? col : -1;
        }
        float ac[4];
        #pragma unroll
        for (int q = 0; q < 4; q++) {
            uint4 m0 = mo[q][0], m1 = mo[q][1];
            float s0 = *(const float*)(rsb + (m0.x & 0xffffu))
                     + *(const float*)(rsb + (m0.x >> 16));
            float s1 = *(const float*)(rsb + (m0.y & 0xffffu))
                     + *(const float*)(rsb + (m0.y >> 16));
            float s2 = *(const float*)(rsb + (m0.z & 0xffffu))
                     + *(const float*)(rsb + (m0.z >> 16));
            float s3 = *(const float*)(rsb + (m0.w & 0xffffu))
                     + *(const float*)(rsb + (m0.w >> 16));
            float s4 = *(const float*)(rsb + (m1.x & 0xffffu))
                     + *(const float*)(rsb + (m1.x >> 16));
            float s5 = *(const float*)(rsb + (m1.y & 0xffffu))
                     + *(const float*)(rsb + (m1.y >> 16));
            float s6 = *(const float*)(rsb + (m1.z & 0xffffu))
                     + *(const float*)(rsb + (m1.z >> 16));
            float s7 = *(const float*)(rsb + (m1.w & 0xffffu))
                     + *(const float*)(rsb + (m1.w >> 16));
            ac[q] = ((s0 + s1) + (s2 + s3)) + ((s4 + s5) + (s6 + s7));
        }
        #pragma unroll
        for (int q = 0; q < 4; q++) {
            int col = cols[q];
            if (col < 0) continue;
            float acc = ac[q];
            if (ci[q] & 1) {  // rare overflow (>8 nnz in either adjacency)
                for (int a = 0; a < 2; a++) {
                    int b = a * NN + col;
                    int cnt = nnzc[b];
                    if (cnt > 8) {
                        const int* cp = colsa + (size_t)b * MAXNNZ;
                        for (int k = 8; k < cnt; k++)
                            acc += rs[(cp[k] & (HB - 1)) + (a ? 2056 : 0)];
                    }
                }
            }
            float kv = c_add + acc;
            if (MODE == 0) {
                const float PIF = 3.14159265358979323846f;
                const float INV2PI = 0.15915494309189535f;
                float pp = sr * svec[col];
                float cc = kv / pp;
                cc = fminf(fmaxf(cc, -1.f + 1e-6f), 1.f - 1e-6f);
                float th = acosf(cc);
                float sth = sqrtf(fmaxf(1.f - cc * cc, 0.f));
                kv = INV2PI * (sth + (PIF - th) * cc) * pp;
                out_b[(size_t)r * NN + col] = f2bf(kv);
            } else {
                out_f[(size_t)r * NN + col] = kv;  // unscaled upper
                int c_rel = col - cbase;
                if (zone == 1) dsum += (double)kv;
                else dsum += (c_rel == by) ? (double)kv : 2.0 * (double)kv;
            }
        }
    }

    if (MODE == 1) {
        red[t] = dsum;
        __syncthreads();
        for (int off = 128; off; off >>= 1) {
            if (t < off) red[t] += red[t + off];
            __syncthreads();
        }
        if (t == 0) atomicAdd(&sums[zone], red[0]);  // zone0->ss, zone1->st, zone2->tt
    }
}

// ---------------- mirror bf16 upper -> lower (tiled LDS transpose) ----------------
__global__ __launch_bounds__(256) void mirror_kernel(ushort* Kb) {
    int bi = blockIdx.x;
    int bj = blockIdx.y;
    if (bj < bi) return;
    __shared__ ushort lds[64][66];
    int R0 = bi * 64, C0 = bj * 64;
    int t = threadIdx.x;
    #pragma unroll
    for (int k = 0; k < 16; k++) {
        int lin = k * 256 + t;
        int row = lin >> 6, col = lin & 63;
        lds[row][col] = Kb[(size_t)(R0 + row) * NN + C0 + col];
    }
    __syncthreads();
    if (bj > bi) {
        #pragma unroll
        for (int k = 0; k < 16; k++) {
            int lin = k * 256 + t;
            int row = lin >> 6, col = lin & 63;
            Kb[(size_t)(C0 + row) * NN + R0 + col] = lds[col][row];
        }
    } else {
        #pragma unroll
        for (int k = 0; k < 16; k++) {
            int lin = k * 256 + t;
            int row = lin >> 6, col = lin & 63;
            if (row > col) Kb[(size_t)(R0 + row) * NN + R0 + col] = lds[col][row];
        }
    }
}

// ---------------- finalize: scale upper in place + write scaled transpose to lower ----------------
__global__ __launch_bounds__(256) void finalize_kernel(float* out, const double* sums) {
    int bi = blockIdx.x;
    int bj = blockIdx.y;
    if (bj < bi) return;
    __shared__ float lds[64][65];
    const double inv = 1.0 / (2048.0 * 2048.0);
    float mss = (float)(sums[0] * inv);
    float mst = (float)(sums[1] * inv);
    float mtt = (float)(sums[2] * inv);
    int R0 = bi * 64, C0 = bj * 64;
    float m = (R0 < SS) ? (C0 < SS ? mss : mst) : (C0 < SS ? mst : mtt);
    int t = threadIdx.x;
    #pragma unroll
    for (int k = 0; k < 16; k++) {
        int lin = k * 256 + t;
        int row = lin >> 6, col = lin & 63;
        lds[row][col] = out[(size_t)(R0 + row) * NN + C0 + col];
    }
    __syncthreads();
    if (bj > bi) {
        #pragma unroll
        for (int k = 0; k < 16; k++) {
            int lin = k * 256 + t;
            int row = lin >> 6, col = lin & 63;
            out[(size_t)(R0 + row) * NN + C0 + col] = m * lds[row][col];
            out[(size_t)(C0 + row) * NN + R0 + col] = m * lds[col][row];
        }
    } else {
        #pragma unroll
        for (int k = 0; k < 16; k++) {
            int lin = k * 256 + t;
            int row = lin >> 6, col = lin & 63;
            float v = (row <= col) ? lds[row][col] : lds[col][row];
            out[(size_t)(R0 + row) * NN + R0 + col] = m * v;
        }
    }
}

extern "C" void kernel_launch(void* const* d_in, const int* in_sizes, int n_in,
                              void* d_out, int out_size, void* d_ws, size_t ws_size,
                              hipStream_t stream) {
    const float* feat = (const float*)d_in[0];
    const float* adj  = (const float*)d_in[1];
    const float* rls  = (const float*)d_in[2];
    const float* rvw  = (const float*)d_in[3];
    const float* rsw  = (const float*)d_in[4];
    const float* rsb  = (const float*)d_in[5];
    const float* rsa  = (const float*)d_in[6];
    const float* rta  = (const float*)d_in[7];
    float* out = (float*)d_out;

    const size_t PNN = (size_t)NN * NN;
    char* p = (char*)d_ws;
    auto alloc = [&](size_t bytes) {
        char* r = p;
        p += (bytes + 255) & ~(size_t)255;
        return r;
    };
    float*  params   = (float*)alloc(64);
    double* sums     = (double*)alloc(64);
    float*  xn       = (float*)alloc((size_t)NN * 4);
    float*  svec     = (float*)alloc((size_t)NN * 4);
    int*    nnzc     = (int*)alloc((size_t)2 * NN * 4);
    int*    colsa    = (int*)alloc((size_t)2 * NN * MAXNNZ * 4);
    ushort* moff     = (ushort*)alloc((size_t)NN * 16 * 2);
    ushort* colinfo  = (ushort*)alloc((size_t)NN * 2);
    ushort* xb       = (ushort*)alloc((size_t)NN * DD * 2);
    ushort* cb0      = (ushort*)alloc(PNN * 2);   // 32 MiB bf16 C0
    ushort* kb1      = (ushort*)alloc(PNN * 2);   // 32 MiB bf16 relu(K1)

    params_kernel<<<1, 64, 0, stream>>>(rls, rvw, rsw, rsb, rsa, rta, params, sums);
    xb_kernel<<<NN, 64, 0, stream>>>(feat, params, xb, xn);
    c0_mfma_kernel<<<dim3(NN / 128, NN / 128), 256, 0, stream>>>(xb, xn, cb0);
    extract_kernel<<<NADJ * NN, 64, 0, stream>>>(adj, nnzc, colsa);
    merge_kernel<<<(NN + 255) / 256, 256, 0, stream>>>(nnzc, colsa, moff, colinfo);

    // svec = sqrt(diag(layer1 K)) from double-gather on C0
    diag1_kernel<<<NN / 4, 256, 0, stream>>>(cb0, nnzc, colsa, params, svec);

    // layer 1 (upper only): C0 (bf16) -> relu_cov(K1) (bf16), then mirror to full
    conv_kernel<0><<<dim3(3, HB), 256, 0, stream>>>(cb0, nnzc, colsa, (const uint4*)moff,
                                                    colinfo, params, svec, kb1, sums);
    mirror_kernel<<<dim3(64, 64), 256, 0, stream>>>(kb1);

    // layer 2 (upper only): K1 (bf16) -> unscaled K2 (fp32) in d_out + block sums
    conv_kernel<1><<<dim3(3, HB), 256, 0, stream>>>(kb1, nnzc, colsa, (const uint4*)moff,
                                                    colinfo, params, svec, out, sums);

    // scale by block means + fill lower triangle (transpose)
    finalize_kernel<<<dim3(64, 64), 256, 0, stream>>>(out, sums);
}